// Round 8
// baseline (155.100 us; speedup 1.0000x reference)
//
#include <hip/hip_runtime.h>
#include <math.h>

#define DDIM 2048
#define KP 8
#define BLOCK 256
#define WPB (BLOCK / 64)

typedef float f4 __attribute__((ext_vector_type(4)));

__device__ __forceinline__ unsigned short f32_to_bf16_rne(float f) {
    unsigned u = __float_as_uint(f);
    unsigned r = u + 0x7FFFu + ((u >> 16) & 1u);
    return (unsigned short)(r >> 16);
}

__device__ __forceinline__ float gelu_f(float x) {
    // 0.5*x*(1+tanh(y)) == x * sigmoid(2y),  y = 0.79788456*(x+0.044715x^3)
    float x2 = x * x;
    float inner = x * fmaf(0.044715f, x2, 1.0f);
    float e = __expf(-1.5957691216057308f * inner);   // exp(-2y)
    return x * __builtin_amdgcn_rcpf(1.0f + e);
}

__device__ __forceinline__ float wave_reduce_add(float v) {
#pragma unroll
    for (int m = 32; m >= 1; m >>= 1) v += __shfl_xor(v, m, 64);
    return v;
}

// Prologue: inv_pn[k] = 1/max(||bf16(protos_k)||, eps)  (norm of ROUNDED protos,
// consistent with the bf16 values the gate kernel dots against)
__global__ void proto_norm_kernel(const float* __restrict__ protos,
                                  float* __restrict__ inv_pn) {
    const int k = blockIdx.x;
    const int tid = threadIdx.x;
    const float* p = protos + k * DDIM;
    float ss = 0.0f;
#pragma unroll
    for (int i = 0; i < 2; ++i) {
        f4 a = reinterpret_cast<const f4*>(p)[tid + i * 256];
        float q;
        q = __uint_as_float((unsigned)f32_to_bf16_rne(a.x) << 16); ss += q * q;
        q = __uint_as_float((unsigned)f32_to_bf16_rne(a.y) << 16); ss += q * q;
        q = __uint_as_float((unsigned)f32_to_bf16_rne(a.z) << 16); ss += q * q;
        q = __uint_as_float((unsigned)f32_to_bf16_rne(a.w) << 16); ss += q * q;
    }
    ss = wave_reduce_add(ss);
    __shared__ float red[4];
    const int wave = tid >> 6, lane = tid & 63;
    if (lane == 0) red[wave] = ss;
    __syncthreads();
    if (tid == 0) {
        float s = red[0] + red[1] + red[2] + red[3];
        inv_pn[k] = 1.0f / fmaxf(sqrtf(s), 1e-12f);
    }
}

// PASS 1: wave-per-row gate computation. gelu values are DISCARDED after
// accumulation -> tiny live set -> high occupancy, no spills (R6 lesson:
// keeping g[8] live forced 160 VGPR / 3 waves per SIMD / 78% stall).
__global__ __launch_bounds__(BLOCK)
void gate_kernel(const float* __restrict__ x,
                 const float* __restrict__ protos,
                 const float* __restrict__ lt,
                 const float* __restrict__ lg,
                 const float* __restrict__ lb,
                 const float* __restrict__ inv_pn,
                 float* __restrict__ gate_out, int nrows) {
    __shared__ unsigned short plb[KP * DDIM];  // 32 KB bf16 proto bank

    const int tid = threadIdx.x;
    const int lane = tid & 63;

    // Stage protos global(fp32) -> LDS(bf16), once per block.
    {
        const f4* ps = reinterpret_cast<const f4*>(protos);
#pragma unroll
        for (int i = 0; i < (KP * DDIM / 4) / BLOCK; ++i) {
            int idx = i * BLOCK + tid;
            f4 v = ps[idx];
            ushort4 u;
            u.x = f32_to_bf16_rne(v.x); u.y = f32_to_bf16_rne(v.y);
            u.z = f32_to_bf16_rne(v.z); u.w = f32_to_bf16_rne(v.w);
            *reinterpret_cast<ushort4*>(&plb[idx * 4]) = u;
        }
    }

    const float tau = __expf(lt[0]);
    const float gamma = __expf(lg[0]);
    const float alpha = 1.0f / (1.0f + __expf(-lb[0]));
    const float inv_tau = 1.0f / tau;
    const float logK_div_tau = logf(8.0f) * inv_tau;

    float ipn[KP];
#pragma unroll
    for (int k = 0; k < KP; ++k) ipn[k] = inv_pn[k];

    __syncthreads();  // the only barrier

    const int gwave = blockIdx.x * WPB + (tid >> 6);
    const int nwaves = gridDim.x * WPB;

    for (int row = gwave; row < nrows; row += nwaves) {
        const f4* xr = reinterpret_cast<const f4*>(x + (size_t)row * DDIM);

        float ss = 0.0f;
        float acc[KP];
#pragma unroll
        for (int k = 0; k < KP; ++k) acc[k] = 0.0f;

#pragma unroll
        for (int c = 0; c < 8; ++c) {
            f4 v = xr[c * 64 + lane];
            f4 gg;
            gg.x = gelu_f(v.x); gg.y = gelu_f(v.y);
            gg.z = gelu_f(v.z); gg.w = gelu_f(v.w);
            ss += gg.x * gg.x + gg.y * gg.y + gg.z * gg.z + gg.w * gg.w;

            const int ebase = c * 256 + lane * 4;
#pragma unroll
            for (int k = 0; k < KP; ++k) {
                uint2 pu = *reinterpret_cast<const uint2*>(&plb[k * DDIM + ebase]);
                float p0 = __uint_as_float(pu.x << 16);
                float p1 = __uint_as_float(pu.x & 0xFFFF0000u);
                float p2 = __uint_as_float(pu.y << 16);
                float p3 = __uint_as_float(pu.y & 0xFFFF0000u);
                acc[k] = fmaf(p0, gg.x,
                         fmaf(p1, gg.y,
                         fmaf(p2, gg.z,
                         fmaf(p3, gg.w, acc[k]))));
            }
            // gg dies here -> not live across the reduction
        }

        ss = wave_reduce_add(ss);
#pragma unroll
        for (int k = 0; k < KP; ++k) acc[k] = wave_reduce_add(acc[k]);

        const float invn = 1.0f / fmaxf(sqrtf(ss), 1e-12f);
        float m = -1e30f;
        float z[KP];
#pragma unroll
        for (int k = 0; k < KP; ++k) {
            z[k] = acc[k] * invn * ipn[k] * tau;
            m = fmaxf(m, z[k]);
        }
        float e = 0.0f;
#pragma unroll
        for (int k = 0; k < KP; ++k) e += __expf(z[k] - m);
        float lse = m + __logf(e);
        float sms = lse * inv_tau - logK_div_tau;
        float nov = __expf(-gamma * sms);
        if (lane == 0) gate_out[row] = 1.0f - alpha + alpha * nov;
    }
}

// PASS 2: pure streaming out = gelu(x) * gate[row]. gelu recomputed with the
// identical f32 formula -> identical values. ~30 VGPR, full occupancy.
__global__ __launch_bounds__(BLOCK)
void scale_kernel(const float* __restrict__ x,
                  const float* __restrict__ gate,
                  float* __restrict__ out, int n4) {
    int idx = blockIdx.x * BLOCK + threadIdx.x;
    const int stride = gridDim.x * BLOCK;
    const f4* x4 = reinterpret_cast<const f4*>(x);
    f4* o4 = reinterpret_cast<f4*>(out);
    for (; idx < n4; idx += stride) {
        f4 v = x4[idx];
        const float gt = gate[idx >> 9];   // 512 f4-chunks per row
        f4 o;
        o.x = gelu_f(v.x) * gt; o.y = gelu_f(v.y) * gt;
        o.z = gelu_f(v.z) * gt; o.w = gelu_f(v.w) * gt;
        __builtin_nontemporal_store(o, &o4[idx]);
    }
}

extern "C" void kernel_launch(void* const* d_in, const int* in_sizes, int n_in,
                              void* d_out, int out_size, void* d_ws, size_t ws_size,
                              hipStream_t stream) {
    const float* x = (const float*)d_in[0];
    const float* protos = (const float*)d_in[1];
    const float* lt = (const float*)d_in[2];
    const float* lg = (const float*)d_in[3];
    const float* lb = (const float*)d_in[4];
    float* out = (float*)d_out;

    float* inv_pn = (float*)d_ws;                      // 8 floats
    float* gate = (float*)((char*)d_ws + 256);         // nrows floats

    const int nrows = in_sizes[0] / DDIM;
    const int n4 = in_sizes[0] / 4;

    proto_norm_kernel<<<KP, 256, 0, stream>>>(protos, inv_pn);

    // one wave per row exactly
    gate_kernel<<<(nrows + WPB - 1) / WPB, BLOCK, 0, stream>>>(
        x, protos, lt, lg, lb, inv_pn, gate, nrows);

    scale_kernel<<<2048, BLOCK, 0, stream>>>(x, gate, out, n4);
}

// Round 9
// 63.312 us; speedup vs baseline: 2.4498x; 2.4498x over previous
//
#include <hip/hip_runtime.h>
#include <math.h>

#define DDIM 2048
#define KP 8
#define BLOCK 256

typedef float f4 __attribute__((ext_vector_type(4)));

__device__ __forceinline__ unsigned short f32_to_bf16_rne(float f) {
    unsigned u = __float_as_uint(f);
    unsigned r = u + 0x7FFFu + ((u >> 16) & 1u);
    return (unsigned short)(r >> 16);
}

__device__ __forceinline__ float gelu_f(float x) {
    // 0.5*x*(1+tanh(y)) == x * sigmoid(2y),  y = 0.79788456*(x+0.044715x^3)
    float x2 = x * x;
    float inner = x * fmaf(0.044715f, x2, 1.0f);
    float e = __expf(-1.5957691216057308f * inner);   // exp(-2y)
    return x * __builtin_amdgcn_rcpf(1.0f + e);
}

__device__ __forceinline__ float wave_reduce_add(float v) {
#pragma unroll
    for (int m = 32; m >= 1; m >>= 1) v += __shfl_xor(v, m, 64);
    return v;
}

// Prologue: pb = bf16(protos) (32 KB, later L1-resident for the main kernel);
// inv_pn[k] = 1/max(||bf16(proto_k)||, eps)  (norm of the ROUNDED values).
__global__ void proto_prep_kernel(const float* __restrict__ protos,
                                  unsigned short* __restrict__ pb,
                                  float* __restrict__ inv_pn) {
    const int k = blockIdx.x;
    const int tid = threadIdx.x;
    const float* p = protos + k * DDIM;
    float ss = 0.0f;
#pragma unroll
    for (int i = 0; i < 2; ++i) {
        int idx = tid + i * 256;                       // f4 index within row
        f4 a = reinterpret_cast<const f4*>(p)[idx];
        ushort4 u;
        u.x = f32_to_bf16_rne(a.x); u.y = f32_to_bf16_rne(a.y);
        u.z = f32_to_bf16_rne(a.z); u.w = f32_to_bf16_rne(a.w);
        float q;
        q = __uint_as_float((unsigned)u.x << 16); ss += q * q;
        q = __uint_as_float((unsigned)u.y << 16); ss += q * q;
        q = __uint_as_float((unsigned)u.z << 16); ss += q * q;
        q = __uint_as_float((unsigned)u.w << 16); ss += q * q;
        *reinterpret_cast<ushort4*>(&pb[(size_t)k * DDIM + idx * 4]) = u;
    }
    ss = wave_reduce_add(ss);
    __shared__ float red[4];
    const int wave = tid >> 6, lane = tid & 63;
    if (lane == 0) red[wave] = ss;
    __syncthreads();
    if (tid == 0)
        inv_pn[k] = 1.0f / fmaxf(sqrtf(red[0] + red[1] + red[2] + red[3]), 1e-12f);
}

// Block-per-row: 8 elements/thread -> small live set (no 150-VGPR wave-per-row
// pathology, R6/R7 lesson). No LDS proto staging (R7 lesson: staging cost
// dominates short blocks) - bf16 protos read from global, L1-resident 32 KB.
// No serial tid0 section (R0 lesson): gate computed redundantly by all threads.
// One barrier/row via double-buffered 288B reduction scratch.
__global__ __launch_bounds__(BLOCK)
void fused_row_kernel(const float* __restrict__ x,
                      const unsigned short* __restrict__ pb,
                      const float* __restrict__ lt,
                      const float* __restrict__ lg,
                      const float* __restrict__ lb,
                      const float* __restrict__ inv_pn,
                      float* __restrict__ out, int nrows) {
    alignas(16) __shared__ float red[2][9][4];   // [buf][value][wave]

    const int tid = threadIdx.x;
    const int lane = tid & 63;
    const int wave = tid >> 6;

    const float tau = __expf(lt[0]);
    const float gamma = __expf(lg[0]);
    const float alpha = 1.0f / (1.0f + __expf(-lb[0]));
    const float inv_tau = 1.0f / tau;
    const float logK_div_tau = logf(8.0f) * inv_tau;

    float ipn[KP];
#pragma unroll
    for (int k = 0; k < KP; ++k) ipn[k] = inv_pn[k];

    const uint2* pb2 = reinterpret_cast<const uint2*>(pb);  // 4 bf16 per uint2

    int buf = 0;
    for (int row = blockIdx.x; row < nrows; row += gridDim.x) {
        const f4* xr = reinterpret_cast<const f4*>(x + (size_t)row * DDIM);
        f4 a = xr[tid];          // elements 4t .. 4t+3
        f4 b = xr[tid + 256];    // elements 1024+4t .. 1024+4t+3

        f4 ga, gb;
        ga.x = gelu_f(a.x); ga.y = gelu_f(a.y);
        ga.z = gelu_f(a.z); ga.w = gelu_f(a.w);
        gb.x = gelu_f(b.x); gb.y = gelu_f(b.y);
        gb.z = gelu_f(b.z); gb.w = gelu_f(b.w);

        float vals[9];
        vals[8] = ga.x * ga.x + ga.y * ga.y + ga.z * ga.z + ga.w * ga.w
                + gb.x * gb.x + gb.y * gb.y + gb.z * gb.z + gb.w * gb.w;

#pragma unroll
        for (int k = 0; k < KP; ++k) {
            // proto k, elements 4t.. and 1024+4t.. as 4xbf16 packs
            uint2 p0 = pb2[k * 512 + tid];
            uint2 p1 = pb2[k * 512 + 256 + tid];
            float q0 = __uint_as_float(p0.x << 16);
            float q1 = __uint_as_float(p0.x & 0xFFFF0000u);
            float q2 = __uint_as_float(p0.y << 16);
            float q3 = __uint_as_float(p0.y & 0xFFFF0000u);
            float r0 = __uint_as_float(p1.x << 16);
            float r1 = __uint_as_float(p1.x & 0xFFFF0000u);
            float r2 = __uint_as_float(p1.y << 16);
            float r3 = __uint_as_float(p1.y & 0xFFFF0000u);
            float t;
            t = fmaf(q0, ga.x, q1 * ga.y);
            t = fmaf(q2, ga.z, t);
            t = fmaf(q3, ga.w, t);
            t = fmaf(r0, gb.x, t);
            t = fmaf(r1, gb.y, t);
            t = fmaf(r2, gb.z, t);
            t = fmaf(r3, gb.w, t);
            vals[k] = t;
        }

        // in-wave butterfly (all lanes end with the wave sum)
#pragma unroll
        for (int v = 0; v < 9; ++v) vals[v] = wave_reduce_add(vals[v]);

        if (lane == 0) {
#pragma unroll
            for (int v = 0; v < 9; ++v) red[buf][v][wave] = vals[v];
        }
        __syncthreads();   // the only barrier per row (red is double-buffered)

        float s[9];
#pragma unroll
        for (int v = 0; v < 9; ++v) {
            f4 r = *reinterpret_cast<const f4*>(red[buf][v]);  // broadcast b128
            s[v] = (r.x + r.y) + (r.z + r.w);
        }
        buf ^= 1;

        // gate, redundantly in every thread (no serial section)
        const float invn = 1.0f / fmaxf(sqrtf(s[8]), 1e-12f);
        float m = -1e30f;
        float z[KP];
#pragma unroll
        for (int k = 0; k < KP; ++k) {
            z[k] = s[k] * invn * ipn[k] * tau;
            m = fmaxf(m, z[k]);
        }
        float e = 0.0f;
#pragma unroll
        for (int k = 0; k < KP; ++k) e += __expf(z[k] - m);
        float lse = m + __logf(e);
        float sms = lse * inv_tau - logK_div_tau;
        float nov = __expf(-gamma * sms);
        const float gate = 1.0f - alpha + alpha * nov;

        f4* orow = reinterpret_cast<f4*>(out + (size_t)row * DDIM);
        f4 oa, ob;
        oa.x = ga.x * gate; oa.y = ga.y * gate;
        oa.z = ga.z * gate; oa.w = ga.w * gate;
        ob.x = gb.x * gate; ob.y = gb.y * gate;
        ob.z = gb.z * gate; ob.w = gb.w * gate;
        __builtin_nontemporal_store(oa, &orow[tid]);
        __builtin_nontemporal_store(ob, &orow[tid + 256]);
    }
}

extern "C" void kernel_launch(void* const* d_in, const int* in_sizes, int n_in,
                              void* d_out, int out_size, void* d_ws, size_t ws_size,
                              hipStream_t stream) {
    const float* x = (const float*)d_in[0];
    const float* protos = (const float*)d_in[1];
    const float* lt = (const float*)d_in[2];
    const float* lg = (const float*)d_in[3];
    const float* lb = (const float*)d_in[4];
    float* out = (float*)d_out;

    float* inv_pn = (float*)d_ws;                                // 8 floats
    unsigned short* pb = (unsigned short*)((char*)d_ws + 256);   // 32 KB bf16 protos

    const int nrows = in_sizes[0] / DDIM;

    proto_prep_kernel<<<KP, 256, 0, stream>>>(protos, pb, inv_pn);

    int blocks = nrows < 4096 ? nrows : 4096;
    fused_row_kernel<<<blocks, BLOCK, 0, stream>>>(x, pb, lt, lg, lb, inv_pn,
                                                   out, nrows);
}

// Round 10
// 60.476 us; speedup vs baseline: 2.5646x; 1.0469x over previous
//
#include <hip/hip_runtime.h>
#include <math.h>

#define DDIM 2048
#define KP 8
#define BLOCK 256

typedef float f4 __attribute__((ext_vector_type(4)));

#if __has_builtin(__builtin_amdgcn_fdot2_f32_bf16)
#define HAVE_DOT2 1
typedef __bf16 bf2 __attribute__((ext_vector_type(2)));
#else
#define HAVE_DOT2 0
#endif

__device__ __forceinline__ unsigned short f32_to_bf16_rne(float f) {
    unsigned u = __float_as_uint(f);
    unsigned r = u + 0x7FFFu + ((u >> 16) & 1u);
    return (unsigned short)(r >> 16);
}

__device__ __forceinline__ float gelu_f(float x) {
    // 0.5*x*(1+tanh(y)) == x * sigmoid(2y),  y = 0.79788456*(x+0.044715x^3)
    float x2 = x * x;
    float inner = x * fmaf(0.044715f, x2, 1.0f);
    float e = __expf(-1.5957691216057308f * inner);   // exp(-2y)
    return x * __builtin_amdgcn_rcpf(1.0f + e);
}

__device__ __forceinline__ float wave_reduce_add(float v) {
#pragma unroll
    for (int m = 32; m >= 1; m >>= 1) v += __shfl_xor(v, m, 64);
    return v;
}

// Prologue: pb = bf16(protos) (32 KB, L1-resident for the main kernel);
// inv_pn[k] = 1/max(||bf16(proto_k)||, eps)  (norm of the ROUNDED values).
__global__ void proto_prep_kernel(const float* __restrict__ protos,
                                  unsigned short* __restrict__ pb,
                                  float* __restrict__ inv_pn) {
    const int k = blockIdx.x;
    const int tid = threadIdx.x;
    const float* p = protos + k * DDIM;
    float ss = 0.0f;
#pragma unroll
    for (int i = 0; i < 2; ++i) {
        int idx = tid + i * 256;                       // f4 index within row
        f4 a = reinterpret_cast<const f4*>(p)[idx];
        ushort4 u;
        u.x = f32_to_bf16_rne(a.x); u.y = f32_to_bf16_rne(a.y);
        u.z = f32_to_bf16_rne(a.z); u.w = f32_to_bf16_rne(a.w);
        float q;
        q = __uint_as_float((unsigned)u.x << 16); ss += q * q;
        q = __uint_as_float((unsigned)u.y << 16); ss += q * q;
        q = __uint_as_float((unsigned)u.z << 16); ss += q * q;
        q = __uint_as_float((unsigned)u.w << 16); ss += q * q;
        *reinterpret_cast<ushort4*>(&pb[(size_t)k * DDIM + idx * 4]) = u;
    }
    ss = wave_reduce_add(ss);
    __shared__ float red[4];
    const int wave = tid >> 6, lane = tid & 63;
    if (lane == 0) red[wave] = ss;
    __syncthreads();
    if (tid == 0)
        inv_pn[k] = 1.0f / fmaxf(sqrtf(red[0] + red[1] + red[2] + red[3]), 1e-12f);
}

// Block-per-row (R8 skeleton: 8 elem/thread, no LDS proto staging, no serial
// section, 1 barrier/row). R9: bf16 dot2 for the proto dots (-30% VALU) and
// explicit next-row load prefetch to cover the butterfly/barrier/gate chain.
__global__ __launch_bounds__(BLOCK)
void fused_row_kernel(const float* __restrict__ x,
                      const unsigned short* __restrict__ pb,
                      const float* __restrict__ lt,
                      const float* __restrict__ lg,
                      const float* __restrict__ lb,
                      const float* __restrict__ inv_pn,
                      float* __restrict__ out, int nrows) {
    alignas(16) __shared__ float red[2][9][4];   // [buf][value][wave]

    const int tid = threadIdx.x;
    const int lane = tid & 63;
    const int wave = tid >> 6;

    const float tau = __expf(lt[0]);
    const float gamma = __expf(lg[0]);
    const float alpha = 1.0f / (1.0f + __expf(-lb[0]));
    const float inv_tau = 1.0f / tau;
    const float logK_div_tau = logf(8.0f) * inv_tau;

    float ipn[KP];
#pragma unroll
    for (int k = 0; k < KP; ++k) ipn[k] = inv_pn[k];

    const uint2* pb2 = reinterpret_cast<const uint2*>(pb);  // 4 bf16 per uint2

    int buf = 0;
    int row = blockIdx.x;
    f4 a, b;
    if (row < nrows) {
        const f4* xr = reinterpret_cast<const f4*>(x + (size_t)row * DDIM);
        a = xr[tid];
        b = xr[tid + 256];
    }

    for (; row < nrows; row += gridDim.x) {
        // prefetch next row's x early: covers butterfly+barrier+gate latency
        const int nxt = row + gridDim.x;
        f4 na, nb;
        if (nxt < nrows) {
            const f4* xn = reinterpret_cast<const f4*>(x + (size_t)nxt * DDIM);
            na = xn[tid];
            nb = xn[tid + 256];
        }

        f4 ga, gb;
        ga.x = gelu_f(a.x); ga.y = gelu_f(a.y);
        ga.z = gelu_f(a.z); ga.w = gelu_f(a.w);
        gb.x = gelu_f(b.x); gb.y = gelu_f(b.y);
        gb.z = gelu_f(b.z); gb.w = gelu_f(b.w);

        float vals[9];
        vals[8] = ga.x * ga.x + ga.y * ga.y + ga.z * ga.z + ga.w * ga.w
                + gb.x * gb.x + gb.y * gb.y + gb.z * gb.z + gb.w * gb.w;

#if HAVE_DOT2
        // pack gelu values to bf16 pairs once; 4 dot2 per proto k
        bf2 gp0, gp1, gp2, gp3;
        gp0.x = (__bf16)ga.x; gp0.y = (__bf16)ga.y;
        gp1.x = (__bf16)ga.z; gp1.y = (__bf16)ga.w;
        gp2.x = (__bf16)gb.x; gp2.y = (__bf16)gb.y;
        gp3.x = (__bf16)gb.z; gp3.y = (__bf16)gb.w;
#pragma unroll
        for (int k = 0; k < KP; ++k) {
            uint2 p0 = pb2[k * 512 + tid];
            uint2 p1 = pb2[k * 512 + 256 + tid];
            float t;
            t = __builtin_amdgcn_fdot2_f32_bf16(gp0, __builtin_bit_cast(bf2, p0.x), 0.0f, false);
            t = __builtin_amdgcn_fdot2_f32_bf16(gp1, __builtin_bit_cast(bf2, p0.y), t, false);
            t = __builtin_amdgcn_fdot2_f32_bf16(gp2, __builtin_bit_cast(bf2, p1.x), t, false);
            t = __builtin_amdgcn_fdot2_f32_bf16(gp3, __builtin_bit_cast(bf2, p1.y), t, false);
            vals[k] = t;
        }
#else
#pragma unroll
        for (int k = 0; k < KP; ++k) {
            uint2 p0 = pb2[k * 512 + tid];
            uint2 p1 = pb2[k * 512 + 256 + tid];
            float q0 = __uint_as_float(p0.x << 16);
            float q1 = __uint_as_float(p0.x & 0xFFFF0000u);
            float q2 = __uint_as_float(p0.y << 16);
            float q3 = __uint_as_float(p0.y & 0xFFFF0000u);
            float r0 = __uint_as_float(p1.x << 16);
            float r1 = __uint_as_float(p1.x & 0xFFFF0000u);
            float r2 = __uint_as_float(p1.y << 16);
            float r3 = __uint_as_float(p1.y & 0xFFFF0000u);
            float t;
            t = fmaf(q0, ga.x, q1 * ga.y);
            t = fmaf(q2, ga.z, t);
            t = fmaf(q3, ga.w, t);
            t = fmaf(r0, gb.x, t);
            t = fmaf(r1, gb.y, t);
            t = fmaf(r2, gb.z, t);
            t = fmaf(r3, gb.w, t);
            vals[k] = t;
        }
#endif

        // in-wave butterfly (all lanes end with the wave sum)
#pragma unroll
        for (int v = 0; v < 9; ++v) vals[v] = wave_reduce_add(vals[v]);

        if (lane == 0) {
#pragma unroll
            for (int v = 0; v < 9; ++v) red[buf][v][wave] = vals[v];
        }
        __syncthreads();   // the only barrier per row (red is double-buffered)

        float s[9];
#pragma unroll
        for (int v = 0; v < 9; ++v) {
            f4 r = *reinterpret_cast<const f4*>(red[buf][v]);  // broadcast b128
            s[v] = (r.x + r.y) + (r.z + r.w);
        }
        buf ^= 1;

        // gate, redundantly in every thread (no serial section)
        const float invn = 1.0f / fmaxf(sqrtf(s[8]), 1e-12f);
        float m = -1e30f;
        float z[KP];
#pragma unroll
        for (int k = 0; k < KP; ++k) {
            z[k] = s[k] * invn * ipn[k] * tau;
            m = fmaxf(m, z[k]);
        }
        float e = 0.0f;
#pragma unroll
        for (int k = 0; k < KP; ++k) e += __expf(z[k] - m);
        float lse = m + __logf(e);
        float sms = lse * inv_tau - logK_div_tau;
        float nov = __expf(-gamma * sms);
        const float gate = 1.0f - alpha + alpha * nov;

        f4* orow = reinterpret_cast<f4*>(out + (size_t)row * DDIM);
        f4 oa, ob;
        oa.x = ga.x * gate; oa.y = ga.y * gate;
        oa.z = ga.z * gate; oa.w = ga.w * gate;
        ob.x = gb.x * gate; ob.y = gb.y * gate;
        ob.z = gb.z * gate; ob.w = gb.w * gate;
        __builtin_nontemporal_store(oa, &orow[tid]);
        __builtin_nontemporal_store(ob, &orow[tid + 256]);

        a = na;
        b = nb;
    }
}

extern "C" void kernel_launch(void* const* d_in, const int* in_sizes, int n_in,
                              void* d_out, int out_size, void* d_ws, size_t ws_size,
                              hipStream_t stream) {
    const float* x = (const float*)d_in[0];
    const float* protos = (const float*)d_in[1];
    const float* lt = (const float*)d_in[2];
    const float* lg = (const float*)d_in[3];
    const float* lb = (const float*)d_in[4];
    float* out = (float*)d_out;

    float* inv_pn = (float*)d_ws;                                // 8 floats
    unsigned short* pb = (unsigned short*)((char*)d_ws + 256);   // 32 KB bf16 protos

    const int nrows = in_sizes[0] / DDIM;

    proto_prep_kernel<<<KP, 256, 0, stream>>>(protos, pb, inv_pn);

    int blocks = nrows < 4096 ? nrows : 4096;
    fused_row_kernel<<<blocks, BLOCK, 0, stream>>>(x, pb, lt, lg, lb, inv_pn,
                                                   out, nrows);
}

// Round 11
// 52.167 us; speedup vs baseline: 2.9731x; 1.1593x over previous
//
#include <hip/hip_runtime.h>
#include <math.h>

#define DDIM 2048
#define KP 8
#define BLOCK 256

typedef float f4 __attribute__((ext_vector_type(4)));

#if __has_builtin(__builtin_amdgcn_fdot2_f32_bf16)
#define HAVE_DOT2 1
typedef __bf16 bf2 __attribute__((ext_vector_type(2)));
#else
#define HAVE_DOT2 0
#endif

#if __has_builtin(__builtin_amdgcn_update_dpp)
#define HAVE_DPP 1
#else
#define HAVE_DPP 0
#endif

__device__ __forceinline__ unsigned short f32_to_bf16_rne(float f) {
    unsigned u = __float_as_uint(f);
    unsigned r = u + 0x7FFFu + ((u >> 16) & 1u);
    return (unsigned short)(r >> 16);
}

__device__ __forceinline__ float gelu_f(float x) {
    // 0.5*x*(1+tanh(y)) == x * sigmoid(2y),  y = 0.79788456*(x+0.044715x^3)
    float x2 = x * x;
    float inner = x * fmaf(0.044715f, x2, 1.0f);
    float e = __expf(-1.5957691216057308f * inner);   // exp(-2y)
    return x * __builtin_amdgcn_rcpf(1.0f + e);
}

__device__ __forceinline__ float wave_reduce_add(float v) {
#pragma unroll
    for (int m = 32; m >= 1; m >>= 1) v += __shfl_xor(v, m, 64);
    return v;
}

#if HAVE_DPP
template <int CTRL>
__device__ __forceinline__ float dpp_add(float v) {
    int t = __builtin_amdgcn_update_dpp(0, __builtin_bit_cast(int, v),
                                        CTRL, 0xf, 0xf, true);
    return v + __builtin_bit_cast(float, t);
}
// Wave-64 sum entirely on the VALU pipe (no DS ops). Valid in LANE 63 ONLY.
__device__ __forceinline__ float wave_sum_dpp_lane63(float v) {
    v = dpp_add<0x111>(v);   // row_shr:1
    v = dpp_add<0x112>(v);   // row_shr:2
    v = dpp_add<0x114>(v);   // row_shr:4
    v = dpp_add<0x118>(v);   // row_shr:8  -> lane 15 of each row16 = row sum
    v = dpp_add<0x142>(v);   // row_bcast:15 -> lane63 = row3+row2
    v = dpp_add<0x143>(v);   // row_bcast:31 -> lane63 += (row0+row1)
    return v;
}
#endif

// Prologue: pb = bf16(protos) (32 KB, L1-resident for the main kernel);
// inv_pn[k] = 1/max(||bf16(proto_k)||, eps)  (norm of the ROUNDED values).
__global__ void proto_prep_kernel(const float* __restrict__ protos,
                                  unsigned short* __restrict__ pb,
                                  float* __restrict__ inv_pn) {
    const int k = blockIdx.x;
    const int tid = threadIdx.x;
    const float* p = protos + k * DDIM;
    float ss = 0.0f;
#pragma unroll
    for (int i = 0; i < 2; ++i) {
        int idx = tid + i * 256;                       // f4 index within row
        f4 a = reinterpret_cast<const f4*>(p)[idx];
        ushort4 u;
        u.x = f32_to_bf16_rne(a.x); u.y = f32_to_bf16_rne(a.y);
        u.z = f32_to_bf16_rne(a.z); u.w = f32_to_bf16_rne(a.w);
        float q;
        q = __uint_as_float((unsigned)u.x << 16); ss += q * q;
        q = __uint_as_float((unsigned)u.y << 16); ss += q * q;
        q = __uint_as_float((unsigned)u.z << 16); ss += q * q;
        q = __uint_as_float((unsigned)u.w << 16); ss += q * q;
        *reinterpret_cast<ushort4*>(&pb[(size_t)k * DDIM + idx * 4]) = u;
    }
    ss = wave_reduce_add(ss);
    __shared__ float red[4];
    const int wave = tid >> 6, lane = tid & 63;
    if (lane == 0) red[wave] = ss;
    __syncthreads();
    if (tid == 0)
        inv_pn[k] = 1.0f / fmaxf(sqrtf(red[0] + red[1] + red[2] + red[3]), 1e-12f);
}

// Block-per-row (R8 skeleton). R10: intra-wave reduction moved from the DS
// pipe (54 ds_bpermute/wave-row == the measured bottleneck) to VALU DPP adds;
// lane 63 holds each wave sum and writes the LDS partials.
__global__ __launch_bounds__(BLOCK)
void fused_row_kernel(const float* __restrict__ x,
                      const unsigned short* __restrict__ pb,
                      const float* __restrict__ lt,
                      const float* __restrict__ lg,
                      const float* __restrict__ lb,
                      const float* __restrict__ inv_pn,
                      float* __restrict__ out, int nrows) {
    alignas(16) __shared__ float red[2][9][4];   // [buf][value][wave]

    const int tid = threadIdx.x;
    const int lane = tid & 63;
    const int wave = tid >> 6;

    const float tau = __expf(lt[0]);
    const float gamma = __expf(lg[0]);
    const float alpha = 1.0f / (1.0f + __expf(-lb[0]));
    const float inv_tau = 1.0f / tau;
    const float logK_div_tau = logf(8.0f) * inv_tau;

    float ipn[KP];
#pragma unroll
    for (int k = 0; k < KP; ++k) ipn[k] = inv_pn[k];

    const uint2* pb2 = reinterpret_cast<const uint2*>(pb);  // 4 bf16 per uint2

    int buf = 0;
    int row = blockIdx.x;
    f4 a, b;
    if (row < nrows) {
        const f4* xr = reinterpret_cast<const f4*>(x + (size_t)row * DDIM);
        a = xr[tid];
        b = xr[tid + 256];
    }

    for (; row < nrows; row += gridDim.x) {
        // prefetch next row's x early: covers reduce+barrier+gate latency
        const int nxt = row + gridDim.x;
        f4 na, nb;
        if (nxt < nrows) {
            const f4* xn = reinterpret_cast<const f4*>(x + (size_t)nxt * DDIM);
            na = xn[tid];
            nb = xn[tid + 256];
        }

        f4 ga, gb;
        ga.x = gelu_f(a.x); ga.y = gelu_f(a.y);
        ga.z = gelu_f(a.z); ga.w = gelu_f(a.w);
        gb.x = gelu_f(b.x); gb.y = gelu_f(b.y);
        gb.z = gelu_f(b.z); gb.w = gelu_f(b.w);

        float vals[9];
        vals[8] = ga.x * ga.x + ga.y * ga.y + ga.z * ga.z + ga.w * ga.w
                + gb.x * gb.x + gb.y * gb.y + gb.z * gb.z + gb.w * gb.w;

#if HAVE_DOT2
        // pack gelu values to bf16 pairs once; 4 dot2 per proto k
        bf2 gp0, gp1, gp2, gp3;
        gp0.x = (__bf16)ga.x; gp0.y = (__bf16)ga.y;
        gp1.x = (__bf16)ga.z; gp1.y = (__bf16)ga.w;
        gp2.x = (__bf16)gb.x; gp2.y = (__bf16)gb.y;
        gp3.x = (__bf16)gb.z; gp3.y = (__bf16)gb.w;
#pragma unroll
        for (int k = 0; k < KP; ++k) {
            uint2 p0 = pb2[k * 512 + tid];
            uint2 p1 = pb2[k * 512 + 256 + tid];
            float t;
            t = __builtin_amdgcn_fdot2_f32_bf16(gp0, __builtin_bit_cast(bf2, p0.x), 0.0f, false);
            t = __builtin_amdgcn_fdot2_f32_bf16(gp1, __builtin_bit_cast(bf2, p0.y), t, false);
            t = __builtin_amdgcn_fdot2_f32_bf16(gp2, __builtin_bit_cast(bf2, p1.x), t, false);
            t = __builtin_amdgcn_fdot2_f32_bf16(gp3, __builtin_bit_cast(bf2, p1.y), t, false);
            vals[k] = t;
        }
#else
#pragma unroll
        for (int k = 0; k < KP; ++k) {
            uint2 p0 = pb2[k * 512 + tid];
            uint2 p1 = pb2[k * 512 + 256 + tid];
            float q0 = __uint_as_float(p0.x << 16);
            float q1 = __uint_as_float(p0.x & 0xFFFF0000u);
            float q2 = __uint_as_float(p0.y << 16);
            float q3 = __uint_as_float(p0.y & 0xFFFF0000u);
            float r0 = __uint_as_float(p1.x << 16);
            float r1 = __uint_as_float(p1.x & 0xFFFF0000u);
            float r2 = __uint_as_float(p1.y << 16);
            float r3 = __uint_as_float(p1.y & 0xFFFF0000u);
            float t;
            t = fmaf(q0, ga.x, q1 * ga.y);
            t = fmaf(q2, ga.z, t);
            t = fmaf(q3, ga.w, t);
            t = fmaf(r0, gb.x, t);
            t = fmaf(r1, gb.y, t);
            t = fmaf(r2, gb.z, t);
            t = fmaf(r3, gb.w, t);
            vals[k] = t;
        }
#endif

#if HAVE_DPP
        // VALU-pipe reduction; wave sum valid in lane 63 only
#pragma unroll
        for (int v = 0; v < 9; ++v) vals[v] = wave_sum_dpp_lane63(vals[v]);
        if (lane == 63) {
#pragma unroll
            for (int v = 0; v < 9; ++v) red[buf][v][wave] = vals[v];
        }
#else
#pragma unroll
        for (int v = 0; v < 9; ++v) vals[v] = wave_reduce_add(vals[v]);
        if (lane == 0) {
#pragma unroll
            for (int v = 0; v < 9; ++v) red[buf][v][wave] = vals[v];
        }
#endif
        __syncthreads();   // the only barrier per row (red is double-buffered)

        float s[9];
#pragma unroll
        for (int v = 0; v < 9; ++v) {
            f4 r = *reinterpret_cast<const f4*>(red[buf][v]);  // broadcast b128
            s[v] = (r.x + r.y) + (r.z + r.w);
        }
        buf ^= 1;

        // gate, redundantly in every thread (no serial section)
        const float invn = 1.0f / fmaxf(sqrtf(s[8]), 1e-12f);
        float m = -1e30f;
        float z[KP];
#pragma unroll
        for (int k = 0; k < KP; ++k) {
            z[k] = s[k] * invn * ipn[k] * tau;
            m = fmaxf(m, z[k]);
        }
        float e = 0.0f;
#pragma unroll
        for (int k = 0; k < KP; ++k) e += __expf(z[k] - m);
        float lse = m + __logf(e);
        float sms = lse * inv_tau - logK_div_tau;
        float nov = __expf(-gamma * sms);
        const float gate = 1.0f - alpha + alpha * nov;

        f4* orow = reinterpret_cast<f4*>(out + (size_t)row * DDIM);
        f4 oa, ob;
        oa.x = ga.x * gate; oa.y = ga.y * gate;
        oa.z = ga.z * gate; oa.w = ga.w * gate;
        ob.x = gb.x * gate; ob.y = gb.y * gate;
        ob.z = gb.z * gate; ob.w = gb.w * gate;
        __builtin_nontemporal_store(oa, &orow[tid]);
        __builtin_nontemporal_store(ob, &orow[tid + 256]);

        a = na;
        b = nb;
    }
}

extern "C" void kernel_launch(void* const* d_in, const int* in_sizes, int n_in,
                              void* d_out, int out_size, void* d_ws, size_t ws_size,
                              hipStream_t stream) {
    const float* x = (const float*)d_in[0];
    const float* protos = (const float*)d_in[1];
    const float* lt = (const float*)d_in[2];
    const float* lg = (const float*)d_in[3];
    const float* lb = (const float*)d_in[4];
    float* out = (float*)d_out;

    float* inv_pn = (float*)d_ws;                                // 8 floats
    unsigned short* pb = (unsigned short*)((char*)d_ws + 256);   // 32 KB bf16 protos

    const int nrows = in_sizes[0] / DDIM;

    proto_prep_kernel<<<KP, 256, 0, stream>>>(protos, pb, inv_pn);

    int blocks = nrows < 4096 ? nrows : 4096;
    fused_row_kernel<<<blocks, BLOCK, 0, stream>>>(x, pb, lt, lg, lb, inv_pn,
                                                   out, nrows);
}